// Round 13
// baseline (24.538 us; speedup 1.0000x reference)
//
#include <hip/hip_runtime.h>

typedef float f32x4 __attribute__((ext_vector_type(4)));

#define BLOCK 256   // 4 waves per block, one anchor per wave (main kernel)
#define NBINS 1024  // labels < 1000
#define SLOT  128   // max recorded occurrences per label (avg 16.4, max ~32)

// Build label buckets: items[c*SLOT + r] = i for each occurrence of label c.
// Order within a bucket is atomic-arbitrary; consumers min-reduce, so the
// final output is deterministic.
__global__ void scatter_kernel(const int* __restrict__ labels,
                               int* __restrict__ cnt,
                               int* __restrict__ items,
                               int N) {
    int i = blockIdx.x * blockDim.x + threadIdx.x;
    if (i >= N) return;
    int c = labels[i];
    if ((unsigned)c < NBINS) {
        int r = atomicAdd(&cnt[c], 1);
        if (r < SLOT) items[c * SLOT + r] = i;
    }
}

// Fused resolve+gather: ONE WAVE per anchor.
//  pos: min-reduce over the anchor's label bucket (2 masked loads + 6 shfl)
//       -- replaces the ~1000-label forward scan entirely.
//  neg: 64-wide ballot scan from i+1 (expected 1 iteration).
//  then gather anchor/pos/neg embedding rows and write 3x512 B + valid.
__global__ void __launch_bounds__(BLOCK) triplet_main_kernel(
    const int* __restrict__ labels,
    const int* __restrict__ cnt,
    const int* __restrict__ items,
    const f32x4* __restrict__ emb,    // [N][32]
    f32x4* __restrict__ out,          // [3][N][32]
    float* __restrict__ valid_out,    // [N]
    int N) {

    const int D4 = 32;
    const int INF = 0x7FFFFFFF;
    int lane = threadIdx.x & 63;
    int i = blockIdx.x * (BLOCK >> 6) + (threadIdx.x >> 6);   // anchor
    if (i >= N) return;

    // Early independent load: anchor embedding row (hidden under resolve).
    int d4 = lane & 31;
    f32x4 ea = emb[(size_t)i * D4 + d4];
    int my = labels[i];

    // --- pos via bucket min-reduce ---
    int p = -1;
    int n = ((unsigned)my < NBINS) ? cnt[my] : SLOT + 1;   // wave-uniform
    if (n <= SLOT) {
        int v0 = (lane < n)      ? items[my * SLOT + lane]      : INF;
        int v1 = (lane + 64 < n) ? items[my * SLOT + lane + 64] : INF;
        if (v0 <= i) v0 = INF;
        if (v1 <= i) v1 = INF;
        int v = min(v0, v1);
        #pragma unroll
        for (int off = 32; off > 0; off >>= 1)
            v = min(v, __shfl_xor(v, off));
        if (v != INF) p = v;
    } else {
        // Overflow fallback (never triggers for this input): linear ballot scan.
        for (int base = i + 1; base < N; base += 64) {
            int j = base + lane;
            unsigned long long bs = __ballot(j < N && labels[j] == my);
            if (bs) { p = base + (int)__ffsll(bs) - 1; break; }
        }
    }

    // --- neg via short ballot scan (first differing label, expected gap ~1) ---
    int ng = -1;
    for (int base = i + 1; base < N; base += 64) {
        int j = base + lane;
        unsigned long long bd = __ballot(j < N && labels[j] != my);
        if (bd) { ng = base + (int)__ffsll(bd) - 1; break; }
    }

    float v  = (p >= 0 && ng >= 0) ? 1.0f : 0.0f;
    int   ps = (p  >= 0) ? p  : 0;    // index irrelevant when invalid (row zeroed)
    int   ns = (ng >= 0) ? ng : 0;

    if (lane == 0) valid_out[i] = v;

    // Combined gather: lanes<32 -> neg row, lanes>=32 -> pos row (one instr).
    size_t ND4 = (size_t)N * D4;
    int gsrc = (lane < 32) ? ns : ps;
    f32x4 eg = emb[(size_t)gsrc * D4 + d4];

    // Pass 1: lanes<32 store anchor row (t=0), lanes>=32 store pos row (t=1).
    int   t  = lane >> 5;
    f32x4 r0 = (lane < 32) ? ea : eg;
    out[(size_t)t * ND4 + (size_t)i * D4 + d4] = r0 * v;

    // Pass 2: lanes<32 store neg row (t=2).
    if (lane < 32)
        out[2 * ND4 + (size_t)i * D4 + d4] = eg * v;
}

extern "C" void kernel_launch(void* const* d_in, const int* in_sizes, int n_in,
                              void* d_out, int out_size, void* d_ws, size_t ws_size,
                              hipStream_t stream) {
    const float* emb    = (const float*)d_in[0];
    const int*   labels = (const int*)d_in[1];   // harness passes integers as int32

    int N = in_sizes[1];             // 16384
    int D = in_sizes[0] / N;         // 128 (D4 = 32 hard-wired in kernel)

    float* out       = (float*)d_out;
    float* valid_out = out + (size_t)3 * N * D;  // tail of d_out: [N] valid mask

    int* cnt   = (int*)d_ws;                     // [NBINS]
    int* items = cnt + NBINS;                    // [NBINS][SLOT]

    hipMemsetAsync(cnt, 0, NBINS * sizeof(int), stream);

    int nblk_s = (N + BLOCK - 1) / BLOCK;
    scatter_kernel<<<nblk_s, BLOCK, 0, stream>>>(labels, cnt, items, N);

    int nblk_m = (N * 64 + BLOCK - 1) / BLOCK;   // one wave per anchor
    triplet_main_kernel<<<nblk_m, BLOCK, 0, stream>>>(
        labels, cnt, items, (const f32x4*)emb, (f32x4*)out, valid_out, N);
}